// Round 1
// baseline (3194.784 us; speedup 1.0000x reference)
//
#include <hip/hip_runtime.h>
#include <math.h>

#define N_NODES  50000
#define N_EDGES  800000
#define HID      64
#define OUT_DIM  12
#define N_LAYERS 4
#define N_GRAPHS 512

// ---------------------------------------------------------------------------
// Fused 4-way GEMM: out_j[n][c] = sum_k x[n][k] * W_j[k][c] + b_j[c]
// blockIdx.y selects which of {Wk,Wq,Wv,Ws}. 64-node tile per block,
// 256 threads, each thread computes a 4x4 (node x col) register block.
// ---------------------------------------------------------------------------
__global__ __launch_bounds__(256) void gemm4_kernel(
    const float* __restrict__ x,
    const float* __restrict__ Wk, const float* __restrict__ bk,
    const float* __restrict__ Wq, const float* __restrict__ bq,
    const float* __restrict__ Wv, const float* __restrict__ bv,
    const float* __restrict__ Ws, const float* __restrict__ bs,
    float* __restrict__ ok, float* __restrict__ oq,
    float* __restrict__ ov, float* __restrict__ os)
{
    __shared__ float xs[64][65];   // +1 pad: avoid 16-way bank conflict on column reads
    __shared__ float wsm[64][64];
    const int t = threadIdx.x;
    const int gbase = blockIdx.x * 64;

    const float* W; const float* b; float* o;
    switch (blockIdx.y) {
      case 0:  W = Wk; b = bk; o = ok; break;
      case 1:  W = Wq; b = bq; o = oq; break;
      case 2:  W = Wv; b = bv; o = ov; break;
      default: W = Ws; b = bs; o = os; break;
    }

    // stage x tile (64x64) and W (64x64), float4 loads
    #pragma unroll
    for (int i = 0; i < 4; ++i) {
        int idx = t + i * 256;        // float4 index, 0..1023
        int r   = idx >> 4;
        int c4  = idx & 15;
        int gn  = gbase + r;
        float4 val = make_float4(0.f, 0.f, 0.f, 0.f);
        if (gn < N_NODES) val = *(const float4*)(x + (size_t)gn * HID + c4 * 4);
        xs[r][c4 * 4 + 0] = val.x; xs[r][c4 * 4 + 1] = val.y;
        xs[r][c4 * 4 + 2] = val.z; xs[r][c4 * 4 + 3] = val.w;
        *(float4*)&wsm[r][c4 * 4] = *(const float4*)(W + r * HID + c4 * 4);
    }
    __syncthreads();

    const int cg = (t & 15) * 4;   // col group
    const int ng = (t >> 4) * 4;   // node group within tile

    float acc[4][4];
    #pragma unroll
    for (int i = 0; i < 4; ++i) {
        #pragma unroll
        for (int j = 0; j < 4; ++j) acc[i][j] = b[cg + j];
    }

    #pragma unroll
    for (int k = 0; k < 64; ++k) {
        float xr[4];
        #pragma unroll
        for (int i = 0; i < 4; ++i) xr[i] = xs[ng + i][k];
        float4 w4 = *(float4*)&wsm[k][cg];
        #pragma unroll
        for (int i = 0; i < 4; ++i) {
            acc[i][0] = fmaf(xr[i], w4.x, acc[i][0]);
            acc[i][1] = fmaf(xr[i], w4.y, acc[i][1]);
            acc[i][2] = fmaf(xr[i], w4.z, acc[i][2]);
            acc[i][3] = fmaf(xr[i], w4.w, acc[i][3]);
        }
    }

    #pragma unroll
    for (int i = 0; i < 4; ++i) {
        int gn = gbase + ng + i;
        if (gn < N_NODES) {
            float4 v4 = make_float4(acc[i][0], acc[i][1], acc[i][2], acc[i][3]);
            *(float4*)(o + (size_t)gn * HID + cg) = v4;
        }
    }
}

// ---------------------------------------------------------------------------
// Edge kernel: 16 threads per edge, each handling 4 channels (float4).
// gate = sigmoid(k[dst] + q[src]); atomically add gate * v[src] into agg[dst].
// agg was pre-filled with the skip term s = x@Ws + bs.
// ---------------------------------------------------------------------------
__global__ __launch_bounds__(256) void edge_kernel(
    const int* __restrict__ ei,
    const float* __restrict__ kf,
    const float* __restrict__ qf,
    const float* __restrict__ vf,
    float* __restrict__ agg)
{
    int t = blockIdx.x * 256 + threadIdx.x;
    int e = t >> 4;
    if (e >= N_EDGES) return;
    int c = (t & 15) * 4;

    int src = ei[e];
    int dst = ei[N_EDGES + e];

    float4 kv = *(const float4*)(kf + (size_t)dst * HID + c);
    float4 qv = *(const float4*)(qf + (size_t)src * HID + c);
    float4 vv = *(const float4*)(vf + (size_t)src * HID + c);

    float g0 = 1.f / (1.f + __expf(-(kv.x + qv.x)));
    float g1 = 1.f / (1.f + __expf(-(kv.y + qv.y)));
    float g2 = 1.f / (1.f + __expf(-(kv.z + qv.z)));
    float g3 = 1.f / (1.f + __expf(-(kv.w + qv.w)));

    float* dsta = agg + (size_t)dst * HID + c;
    atomicAdd(dsta + 0, g0 * vv.x);
    atomicAdd(dsta + 1, g1 * vv.y);
    atomicAdd(dsta + 2, g2 * vv.z);
    atomicAdd(dsta + 3, g3 * vv.w);
}

// ---------------------------------------------------------------------------
// Exact GELU in place: 0.5*x*(1+erf(x/sqrt(2)))
// ---------------------------------------------------------------------------
__global__ __launch_bounds__(256) void gelu_kernel(float* __restrict__ a)
{
    int i = blockIdx.x * 256 + threadIdx.x;
    if (i >= N_NODES * HID / 4) return;
    float4* p = (float4*)a;
    float4 xv = p[i];
    xv.x = 0.5f * xv.x * (1.f + erff(xv.x * 0.70710678118f));
    xv.y = 0.5f * xv.y * (1.f + erff(xv.y * 0.70710678118f));
    xv.z = 0.5f * xv.z * (1.f + erff(xv.z * 0.70710678118f));
    xv.w = 0.5f * xv.w * (1.f + erff(xv.w * 0.70710678118f));
    p[i] = xv;
}

// ---------------------------------------------------------------------------
// Mean-pool accumulate: atomic sums per graph + counts
// ---------------------------------------------------------------------------
__global__ __launch_bounds__(256) void pool_kernel(
    const float* __restrict__ x, const int* __restrict__ batch,
    float* __restrict__ sums, float* __restrict__ cnts)
{
    int t = blockIdx.x * 256 + threadIdx.x;
    int n = t >> 4;
    if (n >= N_NODES) return;
    int c = (t & 15) * 4;
    int b = batch[n];
    float4 xv = *(const float4*)(x + (size_t)n * HID + c);
    float* dsta = sums + (size_t)b * HID + c;
    atomicAdd(dsta + 0, xv.x);
    atomicAdd(dsta + 1, xv.y);
    atomicAdd(dsta + 2, xv.z);
    atomicAdd(dsta + 3, xv.w);
    if ((t & 15) == 0) atomicAdd(cnts + b, 1.0f);
}

// ---------------------------------------------------------------------------
// Head: pooled = sums/max(cnt,1); h = relu(pooled@W1+b1); out = h@W2+b2
// one block (64 threads) per graph
// ---------------------------------------------------------------------------
__global__ __launch_bounds__(64) void head_kernel(
    const float* __restrict__ sums, const float* __restrict__ cnts,
    const float* __restrict__ w1, const float* __restrict__ b1,
    const float* __restrict__ w2, const float* __restrict__ b2,
    float* __restrict__ out)
{
    int g = blockIdx.x;
    int t = threadIdx.x;
    __shared__ float p[64];
    __shared__ float h[64];
    float cnt = fmaxf(cnts[g], 1.0f);
    p[t] = sums[(size_t)g * HID + t] / cnt;
    __syncthreads();
    float acc = b1[t];
    #pragma unroll 8
    for (int k = 0; k < HID; ++k) acc = fmaf(p[k], w1[k * HID + t], acc);
    h[t] = fmaxf(acc, 0.f);
    __syncthreads();
    if (t < OUT_DIM) {
        float a2 = b2[t];
        #pragma unroll 8
        for (int k = 0; k < HID; ++k) a2 = fmaf(h[k], w2[k * OUT_DIM + t], a2);
        out[(size_t)g * OUT_DIM + t] = a2;
    }
}

// ---------------------------------------------------------------------------
extern "C" void kernel_launch(void* const* d_in, const int* in_sizes, int n_in,
                              void* d_out, int out_size, void* d_ws, size_t ws_size,
                              hipStream_t stream)
{
    const float* x     = (const float*)d_in[0];
    const int*   ei    = (const int*)d_in[1];
    const int*   batch = (const int*)d_in[2];
    // d_in[3] = batch_size scalar (known constant 512)
    const float* Wk = (const float*)d_in[4];
    const float* bk = (const float*)d_in[5];
    const float* Wq = (const float*)d_in[6];
    const float* bq = (const float*)d_in[7];
    const float* Wv = (const float*)d_in[8];
    const float* bv = (const float*)d_in[9];
    const float* Ws = (const float*)d_in[10];
    const float* bs = (const float*)d_in[11];
    const float* w1 = (const float*)d_in[12];
    const float* b1 = (const float*)d_in[13];
    const float* w2 = (const float*)d_in[14];
    const float* b2 = (const float*)d_in[15];
    float* out = (float*)d_out;

    float* wsf = (float*)d_ws;
    const size_t NF = (size_t)N_NODES * HID;
    float* bufA = wsf;            // x / skip+agg ping
    float* bufB = wsf + NF;       // x / skip+agg pong
    float* bufK = wsf + 2 * NF;
    float* bufQ = wsf + 3 * NF;
    float* bufV = wsf + 4 * NF;
    float* sums = wsf + 5 * NF;               // [512][64]
    float* cnts = sums + (size_t)N_GRAPHS * HID; // [512]

    const int gemm_gx = (N_NODES + 63) / 64;          // 782
    const int edge_g  = N_EDGES / 16;                 // 50000 (exact)
    const int gelu_g  = (N_NODES * HID / 4) / 256;    // 3125 (exact)
    const int pool_g  = (N_NODES * 16 + 255) / 256;   // 3125

    const float* xsrc = x;
    for (int l = 0; l < N_LAYERS; ++l) {
        float* sb = (l & 1) ? bufB : bufA;   // skip-term / aggregation / next-x buffer
        gemm4_kernel<<<dim3(gemm_gx, 4), 256, 0, stream>>>(
            xsrc,
            Wk + (size_t)l * HID * HID, bk + (size_t)l * HID,
            Wq + (size_t)l * HID * HID, bq + (size_t)l * HID,
            Wv + (size_t)l * HID * HID, bv + (size_t)l * HID,
            Ws + (size_t)l * HID * HID, bs + (size_t)l * HID,
            bufK, bufQ, bufV, sb);
        edge_kernel<<<edge_g, 256, 0, stream>>>(ei, bufK, bufQ, bufV, sb);
        gelu_kernel<<<gelu_g, 256, 0, stream>>>(sb);
        xsrc = sb;
    }

    hipMemsetAsync(sums, 0, (size_t)(N_GRAPHS * HID + N_GRAPHS) * sizeof(float), stream);
    pool_kernel<<<pool_g, 256, 0, stream>>>(xsrc, batch, sums, cnts);
    head_kernel<<<N_GRAPHS, 64, 0, stream>>>(sums, cnts, w1, b1, w2, b2, out);
}

// Round 2
// 885.075 us; speedup vs baseline: 3.6096x; 3.6096x over previous
//
#include <hip/hip_runtime.h>
#include <math.h>

#define N_NODES  50000
#define N_EDGES  800000
#define HID      64
#define OUT_DIM  12
#define N_LAYERS 4
#define N_GRAPHS 512

#define SCAN_CHUNK 512
#define N_CHUNKS   ((N_NODES + SCAN_CHUNK - 1) / SCAN_CHUNK)   // 98

// ---------------------------------------------------------------------------
// Fused 4-way GEMM: out_j[n][c] = sum_k x[n][k] * W_j[k][c] + b_j[c]
// blockIdx.y selects which of {Wk,Wq,Wv,Ws}. 64-node tile per block,
// 256 threads, each thread computes a 4x4 (node x col) register block.
// ---------------------------------------------------------------------------
__global__ __launch_bounds__(256) void gemm4_kernel(
    const float* __restrict__ x,
    const float* __restrict__ Wk, const float* __restrict__ bk,
    const float* __restrict__ Wq, const float* __restrict__ bq,
    const float* __restrict__ Wv, const float* __restrict__ bv,
    const float* __restrict__ Ws, const float* __restrict__ bs,
    float* __restrict__ ok, float* __restrict__ oq,
    float* __restrict__ ov, float* __restrict__ os)
{
    __shared__ float xs[64][65];   // +1 pad: avoid bank conflict on column reads
    __shared__ float wsm[64][64];
    const int t = threadIdx.x;
    const int gbase = blockIdx.x * 64;

    const float* W; const float* b; float* o;
    switch (blockIdx.y) {
      case 0:  W = Wk; b = bk; o = ok; break;
      case 1:  W = Wq; b = bq; o = oq; break;
      case 2:  W = Wv; b = bv; o = ov; break;
      default: W = Ws; b = bs; o = os; break;
    }

    #pragma unroll
    for (int i = 0; i < 4; ++i) {
        int idx = t + i * 256;        // float4 index, 0..1023
        int r   = idx >> 4;
        int c4  = idx & 15;
        int gn  = gbase + r;
        float4 val = make_float4(0.f, 0.f, 0.f, 0.f);
        if (gn < N_NODES) val = *(const float4*)(x + (size_t)gn * HID + c4 * 4);
        xs[r][c4 * 4 + 0] = val.x; xs[r][c4 * 4 + 1] = val.y;
        xs[r][c4 * 4 + 2] = val.z; xs[r][c4 * 4 + 3] = val.w;
        *(float4*)&wsm[r][c4 * 4] = *(const float4*)(W + r * HID + c4 * 4);
    }
    __syncthreads();

    const int cg = (t & 15) * 4;   // col group
    const int ng = (t >> 4) * 4;   // node group within tile

    float acc[4][4];
    #pragma unroll
    for (int i = 0; i < 4; ++i) {
        #pragma unroll
        for (int j = 0; j < 4; ++j) acc[i][j] = b[cg + j];
    }

    #pragma unroll
    for (int k = 0; k < 64; ++k) {
        float xr[4];
        #pragma unroll
        for (int i = 0; i < 4; ++i) xr[i] = xs[ng + i][k];
        float4 w4 = *(float4*)&wsm[k][cg];
        #pragma unroll
        for (int i = 0; i < 4; ++i) {
            acc[i][0] = fmaf(xr[i], w4.x, acc[i][0]);
            acc[i][1] = fmaf(xr[i], w4.y, acc[i][1]);
            acc[i][2] = fmaf(xr[i], w4.z, acc[i][2]);
            acc[i][3] = fmaf(xr[i], w4.w, acc[i][3]);
        }
    }

    #pragma unroll
    for (int i = 0; i < 4; ++i) {
        int gn = gbase + ng + i;
        if (gn < N_NODES) {
            float4 v4 = make_float4(acc[i][0], acc[i][1], acc[i][2], acc[i][3]);
            *(float4*)(o + (size_t)gn * HID + cg) = v4;
        }
    }
}

// ---------------------------------------------------------------------------
// CSR build: histogram of dst, exclusive scan, stable-ish scatter of src ids
// ---------------------------------------------------------------------------
__global__ __launch_bounds__(256) void hist_kernel(
    const int* __restrict__ ei, int* __restrict__ deg)
{
    int e = blockIdx.x * 256 + threadIdx.x;
    if (e < N_EDGES) atomicAdd(&deg[ei[N_EDGES + e]], 1);
}

__global__ __launch_bounds__(SCAN_CHUNK) void scan1_kernel(
    const int* __restrict__ deg, int* __restrict__ base, int* __restrict__ blocksum)
{
    __shared__ int s[SCAN_CHUNK];
    int t = threadIdx.x;
    int i = blockIdx.x * SCAN_CHUNK + t;
    int v = (i < N_NODES) ? deg[i] : 0;
    s[t] = v;
    __syncthreads();
    for (int off = 1; off < SCAN_CHUNK; off <<= 1) {
        int u = (t >= off) ? s[t - off] : 0;
        __syncthreads();
        s[t] += u;
        __syncthreads();
    }
    if (i < N_NODES) base[i] = s[t] - v;              // exclusive
    if (t == SCAN_CHUNK - 1) blocksum[blockIdx.x] = s[t];
}

__global__ __launch_bounds__(128) void scan2_kernel(
    const int* __restrict__ blocksum, int* __restrict__ blockoff)
{
    __shared__ int s[128];
    int t = threadIdx.x;
    int v = (t < N_CHUNKS) ? blocksum[t] : 0;
    s[t] = v;
    __syncthreads();
    for (int off = 1; off < 128; off <<= 1) {
        int u = (t >= off) ? s[t - off] : 0;
        __syncthreads();
        s[t] += u;
        __syncthreads();
    }
    if (t < N_CHUNKS) blockoff[t] = s[t] - v;         // exclusive
}

__global__ __launch_bounds__(SCAN_CHUNK) void scan3_kernel(
    int* __restrict__ base, const int* __restrict__ blockoff)
{
    int i = blockIdx.x * SCAN_CHUNK + threadIdx.x;
    if (i < N_NODES) base[i] += blockoff[blockIdx.x];
    if (i == 0) base[N_NODES] = N_EDGES;
}

__global__ __launch_bounds__(256) void scatter_kernel(
    const int* __restrict__ ei, const int* __restrict__ base,
    int* __restrict__ cursor, int* __restrict__ csr_src)
{
    int e = blockIdx.x * 256 + threadIdx.x;
    if (e >= N_EDGES) return;
    int s = ei[e];
    int d = ei[N_EDGES + e];
    int pos = base[d] + atomicAdd(&cursor[d], 1);
    csr_src[pos] = s;
}

// ---------------------------------------------------------------------------
// Gather-side aggregation + skip + GELU, no atomics.
// One wave per node, lane = channel. skip may alias outx (in-place).
// ---------------------------------------------------------------------------
__global__ __launch_bounds__(256) void agg_gelu_kernel(
    const int* __restrict__ base, const int* __restrict__ csr_src,
    const float* __restrict__ kf, const float* __restrict__ qf,
    const float* __restrict__ vf, const float* __restrict__ skip,
    float* __restrict__ outx)
{
    int node = blockIdx.x * 4 + (threadIdx.x >> 6);
    if (node >= N_NODES) return;
    int lane = threadIdx.x & 63;
    int p0 = base[node];
    int p1 = base[node + 1];
    float kd = kf[(size_t)node * HID + lane];
    float acc = 0.f;
    for (int p = p0; p < p1; ++p) {
        int s = csr_src[p];
        float qv = qf[(size_t)s * HID + lane];
        float vv = vf[(size_t)s * HID + lane];
        float g = 1.f / (1.f + __expf(-(kd + qv)));
        acc = fmaf(g, vv, acc);
    }
    float xo = acc + skip[(size_t)node * HID + lane];
    outx[(size_t)node * HID + lane] = 0.5f * xo * (1.f + erff(xo * 0.70710678118f));
}

// ---------------------------------------------------------------------------
// Mean-pool accumulate: atomic sums per graph + counts
// ---------------------------------------------------------------------------
__global__ __launch_bounds__(256) void pool_kernel(
    const float* __restrict__ x, const int* __restrict__ batch,
    float* __restrict__ sums, float* __restrict__ cnts)
{
    int t = blockIdx.x * 256 + threadIdx.x;
    int n = t >> 4;
    if (n >= N_NODES) return;
    int c = (t & 15) * 4;
    int b = batch[n];
    float4 xv = *(const float4*)(x + (size_t)n * HID + c);
    float* dsta = sums + (size_t)b * HID + c;
    atomicAdd(dsta + 0, xv.x);
    atomicAdd(dsta + 1, xv.y);
    atomicAdd(dsta + 2, xv.z);
    atomicAdd(dsta + 3, xv.w);
    if ((t & 15) == 0) atomicAdd(cnts + b, 1.0f);
}

// ---------------------------------------------------------------------------
// Head: pooled = sums/max(cnt,1); h = relu(pooled@W1+b1); out = h@W2+b2
// ---------------------------------------------------------------------------
__global__ __launch_bounds__(64) void head_kernel(
    const float* __restrict__ sums, const float* __restrict__ cnts,
    const float* __restrict__ w1, const float* __restrict__ b1,
    const float* __restrict__ w2, const float* __restrict__ b2,
    float* __restrict__ out)
{
    int g = blockIdx.x;
    int t = threadIdx.x;
    __shared__ float p[64];
    __shared__ float h[64];
    float cnt = fmaxf(cnts[g], 1.0f);
    p[t] = sums[(size_t)g * HID + t] / cnt;
    __syncthreads();
    float acc = b1[t];
    #pragma unroll 8
    for (int k = 0; k < HID; ++k) acc = fmaf(p[k], w1[k * HID + t], acc);
    h[t] = fmaxf(acc, 0.f);
    __syncthreads();
    if (t < OUT_DIM) {
        float a2 = b2[t];
        #pragma unroll 8
        for (int k = 0; k < HID; ++k) a2 = fmaf(h[k], w2[k * OUT_DIM + t], a2);
        out[(size_t)g * OUT_DIM + t] = a2;
    }
}

// ---------------------------------------------------------------------------
extern "C" void kernel_launch(void* const* d_in, const int* in_sizes, int n_in,
                              void* d_out, int out_size, void* d_ws, size_t ws_size,
                              hipStream_t stream)
{
    const float* x     = (const float*)d_in[0];
    const int*   ei    = (const int*)d_in[1];
    const int*   batch = (const int*)d_in[2];
    const float* Wk = (const float*)d_in[4];
    const float* bk = (const float*)d_in[5];
    const float* Wq = (const float*)d_in[6];
    const float* bq = (const float*)d_in[7];
    const float* Wv = (const float*)d_in[8];
    const float* bv = (const float*)d_in[9];
    const float* Ws = (const float*)d_in[10];
    const float* bs = (const float*)d_in[11];
    const float* w1 = (const float*)d_in[12];
    const float* b1 = (const float*)d_in[13];
    const float* w2 = (const float*)d_in[14];
    const float* b2 = (const float*)d_in[15];
    float* out = (float*)d_out;

    float* wsf = (float*)d_ws;
    const size_t NF = (size_t)N_NODES * HID;
    float* bufA = wsf;            // layer output ping
    float* bufB = wsf + NF;       // layer output pong
    float* bufK = wsf + 2 * NF;
    float* bufQ = wsf + 3 * NF;
    float* bufV = wsf + 4 * NF;
    float* sums = wsf + 5 * NF;                   // [512][64]
    float* cnts = sums + (size_t)N_GRAPHS * HID;  // [512]

    // persistent ints (live across all layers)
    int* baseI   = (int*)(cnts + N_GRAPHS);
    int* csr_src = baseI + N_NODES + 1;
    // transient ints for CSR build — overlap bufB (first written in layer 1,
    // after the CSR build is complete)
    int* deg      = (int*)bufB;
    int* cursor   = deg + N_NODES;
    int* blocksum = cursor + N_NODES;
    int* blockoff = blocksum + 128;

    const int gemm_gx = (N_NODES + 63) / 64;          // 782
    const int eg      = (N_EDGES + 255) / 256;        // 3125
    const int agg_g   = (N_NODES + 3) / 4;            // 12500
    const int pool_g  = (N_NODES * 16 + 255) / 256;   // 3125

    // ---- build CSR (dst -> list of src), once per launch ----
    hipMemsetAsync(deg, 0, (size_t)2 * N_NODES * sizeof(int), stream);
    hist_kernel<<<eg, 256, 0, stream>>>(ei, deg);
    scan1_kernel<<<N_CHUNKS, SCAN_CHUNK, 0, stream>>>(deg, baseI, blocksum);
    scan2_kernel<<<1, 128, 0, stream>>>(blocksum, blockoff);
    scan3_kernel<<<N_CHUNKS, SCAN_CHUNK, 0, stream>>>(baseI, blockoff);
    scatter_kernel<<<eg, 256, 0, stream>>>(ei, baseI, cursor, csr_src);

    // ---- layers ----
    const float* xsrc = x;
    for (int l = 0; l < N_LAYERS; ++l) {
        float* sb = (l & 1) ? bufB : bufA;
        gemm4_kernel<<<dim3(gemm_gx, 4), 256, 0, stream>>>(
            xsrc,
            Wk + (size_t)l * HID * HID, bk + (size_t)l * HID,
            Wq + (size_t)l * HID * HID, bq + (size_t)l * HID,
            Wv + (size_t)l * HID * HID, bv + (size_t)l * HID,
            Ws + (size_t)l * HID * HID, bs + (size_t)l * HID,
            bufK, bufQ, bufV, sb);
        agg_gelu_kernel<<<agg_g, 256, 0, stream>>>(
            baseI, csr_src, bufK, bufQ, bufV, sb, sb);
        xsrc = sb;
    }

    // ---- pool + head ----
    hipMemsetAsync(sums, 0, (size_t)(N_GRAPHS * HID + N_GRAPHS) * sizeof(float), stream);
    pool_kernel<<<pool_g, 256, 0, stream>>>(xsrc, batch, sums, cnts);
    head_kernel<<<N_GRAPHS, 64, 0, stream>>>(sums, cnts, w1, b1, w2, b2, out);
}

// Round 3
// 568.899 us; speedup vs baseline: 5.6157x; 1.5558x over previous
//
#include <hip/hip_runtime.h>
#include <math.h>

#define N_NODES  50000
#define N_EDGES  800000
#define HID      64
#define OUT_DIM  12
#define N_LAYERS 4
#define N_GRAPHS 512

#define SCAN_CHUNK 512
#define N_CHUNKS   ((N_NODES + SCAN_CHUNK - 1) / SCAN_CHUNK)   // 98

typedef unsigned short u16;
typedef unsigned int   u32;

__device__ __forceinline__ u16 f2bf(float f) {
    u32 u = __float_as_uint(f);
    u32 r = (u + 0x7FFFu + ((u >> 16) & 1u)) >> 16;   // RNE
    return (u16)r;
}
__device__ __forceinline__ float bf2f(u16 h) {
    return __uint_as_float(((u32)h) << 16);
}

// ---------------------------------------------------------------------------
// Fused 4-way GEMM, single pass over x: k,s stored f32; q,v stored bf16.
// 64-node tile per block, 256 threads, each thread: 4 nodes x 4 cols x 4 mats.
// Weights read from global (16 KB each, L1/L2-resident across 782 blocks).
// ---------------------------------------------------------------------------
__global__ __launch_bounds__(256) void gemm4f_kernel(
    const float* __restrict__ x,
    const float* __restrict__ Wk, const float* __restrict__ bk,
    const float* __restrict__ Wq, const float* __restrict__ bq,
    const float* __restrict__ Wv, const float* __restrict__ bv,
    const float* __restrict__ Ws, const float* __restrict__ bs,
    float* __restrict__ ok, u16* __restrict__ oq,
    u16* __restrict__ ov, float* __restrict__ os)
{
    __shared__ float xs[64][65];   // +1 pad
    const int t = threadIdx.x;
    const int gbase = blockIdx.x * 64;

    #pragma unroll
    for (int i = 0; i < 4; ++i) {
        int idx = t + i * 256;        // float4 index 0..1023
        int r   = idx >> 4;
        int c4  = idx & 15;
        int gn  = gbase + r;
        float4 val = make_float4(0.f, 0.f, 0.f, 0.f);
        if (gn < N_NODES) val = *(const float4*)(x + (size_t)gn * HID + c4 * 4);
        xs[r][c4 * 4 + 0] = val.x; xs[r][c4 * 4 + 1] = val.y;
        xs[r][c4 * 4 + 2] = val.z; xs[r][c4 * 4 + 3] = val.w;
    }
    __syncthreads();

    const int cg = (t & 15) * 4;   // col group
    const int ng = (t >> 4) * 4;   // node group within tile

    float acc[4][4][4];            // [mat][node][col]
    {
        float4 b0 = *(const float4*)(bk + cg);
        float4 b1 = *(const float4*)(bq + cg);
        float4 b2 = *(const float4*)(bv + cg);
        float4 b3 = *(const float4*)(bs + cg);
        #pragma unroll
        for (int i = 0; i < 4; ++i) {
            acc[0][i][0] = b0.x; acc[0][i][1] = b0.y; acc[0][i][2] = b0.z; acc[0][i][3] = b0.w;
            acc[1][i][0] = b1.x; acc[1][i][1] = b1.y; acc[1][i][2] = b1.z; acc[1][i][3] = b1.w;
            acc[2][i][0] = b2.x; acc[2][i][1] = b2.y; acc[2][i][2] = b2.z; acc[2][i][3] = b2.w;
            acc[3][i][0] = b3.x; acc[3][i][1] = b3.y; acc[3][i][2] = b3.z; acc[3][i][3] = b3.w;
        }
    }

    #pragma unroll 8
    for (int k = 0; k < 64; ++k) {
        float xr[4];
        #pragma unroll
        for (int i = 0; i < 4; ++i) xr[i] = xs[ng + i][k];
        float4 w0 = *(const float4*)(Wk + k * HID + cg);
        float4 w1 = *(const float4*)(Wq + k * HID + cg);
        float4 w2 = *(const float4*)(Wv + k * HID + cg);
        float4 w3 = *(const float4*)(Ws + k * HID + cg);
        #pragma unroll
        for (int i = 0; i < 4; ++i) {
            acc[0][i][0] = fmaf(xr[i], w0.x, acc[0][i][0]);
            acc[0][i][1] = fmaf(xr[i], w0.y, acc[0][i][1]);
            acc[0][i][2] = fmaf(xr[i], w0.z, acc[0][i][2]);
            acc[0][i][3] = fmaf(xr[i], w0.w, acc[0][i][3]);
            acc[1][i][0] = fmaf(xr[i], w1.x, acc[1][i][0]);
            acc[1][i][1] = fmaf(xr[i], w1.y, acc[1][i][1]);
            acc[1][i][2] = fmaf(xr[i], w1.z, acc[1][i][2]);
            acc[1][i][3] = fmaf(xr[i], w1.w, acc[1][i][3]);
            acc[2][i][0] = fmaf(xr[i], w2.x, acc[2][i][0]);
            acc[2][i][1] = fmaf(xr[i], w2.y, acc[2][i][1]);
            acc[2][i][2] = fmaf(xr[i], w2.z, acc[2][i][2]);
            acc[2][i][3] = fmaf(xr[i], w2.w, acc[2][i][3]);
            acc[3][i][0] = fmaf(xr[i], w3.x, acc[3][i][0]);
            acc[3][i][1] = fmaf(xr[i], w3.y, acc[3][i][1]);
            acc[3][i][2] = fmaf(xr[i], w3.z, acc[3][i][2]);
            acc[3][i][3] = fmaf(xr[i], w3.w, acc[3][i][3]);
        }
    }

    #pragma unroll
    for (int i = 0; i < 4; ++i) {
        int gn = gbase + ng + i;
        if (gn < N_NODES) {
            size_t off = (size_t)gn * HID + cg;
            *(float4*)(ok + off) = make_float4(acc[0][i][0], acc[0][i][1], acc[0][i][2], acc[0][i][3]);
            *(float4*)(os + off) = make_float4(acc[3][i][0], acc[3][i][1], acc[3][i][2], acc[3][i][3]);
            u32 q01 = (u32)f2bf(acc[1][i][0]) | ((u32)f2bf(acc[1][i][1]) << 16);
            u32 q23 = (u32)f2bf(acc[1][i][2]) | ((u32)f2bf(acc[1][i][3]) << 16);
            u32 v01 = (u32)f2bf(acc[2][i][0]) | ((u32)f2bf(acc[2][i][1]) << 16);
            u32 v23 = (u32)f2bf(acc[2][i][2]) | ((u32)f2bf(acc[2][i][3]) << 16);
            *(uint2*)(oq + off) = make_uint2(q01, q23);
            *(uint2*)(ov + off) = make_uint2(v01, v23);
        }
    }
}

// ---------------------------------------------------------------------------
// CSR build: histogram of dst, exclusive scan, scatter of src ids
// ---------------------------------------------------------------------------
__global__ __launch_bounds__(256) void hist_kernel(
    const int* __restrict__ ei, int* __restrict__ deg)
{
    int e = blockIdx.x * 256 + threadIdx.x;
    if (e < N_EDGES) atomicAdd(&deg[ei[N_EDGES + e]], 1);
}

__global__ __launch_bounds__(SCAN_CHUNK) void scan1_kernel(
    const int* __restrict__ deg, int* __restrict__ base, int* __restrict__ blocksum)
{
    __shared__ int s[SCAN_CHUNK];
    int t = threadIdx.x;
    int i = blockIdx.x * SCAN_CHUNK + t;
    int v = (i < N_NODES) ? deg[i] : 0;
    s[t] = v;
    __syncthreads();
    for (int off = 1; off < SCAN_CHUNK; off <<= 1) {
        int u = (t >= off) ? s[t - off] : 0;
        __syncthreads();
        s[t] += u;
        __syncthreads();
    }
    if (i < N_NODES) base[i] = s[t] - v;              // exclusive
    if (t == SCAN_CHUNK - 1) blocksum[blockIdx.x] = s[t];
}

__global__ __launch_bounds__(128) void scan2_kernel(
    const int* __restrict__ blocksum, int* __restrict__ blockoff)
{
    __shared__ int s[128];
    int t = threadIdx.x;
    int v = (t < N_CHUNKS) ? blocksum[t] : 0;
    s[t] = v;
    __syncthreads();
    for (int off = 1; off < 128; off <<= 1) {
        int u = (t >= off) ? s[t - off] : 0;
        __syncthreads();
        s[t] += u;
        __syncthreads();
    }
    if (t < N_CHUNKS) blockoff[t] = s[t] - v;         // exclusive
}

__global__ __launch_bounds__(SCAN_CHUNK) void scan3_kernel(
    int* __restrict__ base, const int* __restrict__ blockoff)
{
    int i = blockIdx.x * SCAN_CHUNK + threadIdx.x;
    if (i < N_NODES) base[i] += blockoff[blockIdx.x];
    if (i == 0) base[N_NODES] = N_EDGES;
}

__global__ __launch_bounds__(256) void scatter_kernel(
    const int* __restrict__ ei, const int* __restrict__ base,
    int* __restrict__ cursor, int* __restrict__ csr_src)
{
    int e = blockIdx.x * 256 + threadIdx.x;
    if (e >= N_EDGES) return;
    int s = ei[e];
    int d = ei[N_EDGES + e];
    int pos = base[d] + atomicAdd(&cursor[d], 1);
    csr_src[pos] = s;
}

// ---------------------------------------------------------------------------
// Gather-side aggregation + skip + GELU. One wave per node, lane = channel.
// q,v are bf16 (halved gather traffic); k and skip are f32.
// ---------------------------------------------------------------------------
__global__ __launch_bounds__(256) void agg_gelu_kernel(
    const int* __restrict__ base, const int* __restrict__ csr_src,
    const float* __restrict__ kf, const u16* __restrict__ qh,
    const u16* __restrict__ vh, const float* __restrict__ skip,
    float* __restrict__ outx)
{
    int node = blockIdx.x * 4 + (threadIdx.x >> 6);
    if (node >= N_NODES) return;
    int lane = threadIdx.x & 63;
    int p0 = base[node];
    int p1 = base[node + 1];
    float kd = kf[(size_t)node * HID + lane];
    float acc = 0.f;
    int p = p0;
    for (; p + 2 <= p1; p += 2) {
        int s0 = csr_src[p];
        int s1 = csr_src[p + 1];
        float q0 = bf2f(qh[(size_t)s0 * HID + lane]);
        float v0 = bf2f(vh[(size_t)s0 * HID + lane]);
        float q1 = bf2f(qh[(size_t)s1 * HID + lane]);
        float v1 = bf2f(vh[(size_t)s1 * HID + lane]);
        float g0 = 1.f / (1.f + __expf(-(kd + q0)));
        float g1 = 1.f / (1.f + __expf(-(kd + q1)));
        acc = fmaf(g0, v0, acc);
        acc = fmaf(g1, v1, acc);
    }
    if (p < p1) {
        int s0 = csr_src[p];
        float q0 = bf2f(qh[(size_t)s0 * HID + lane]);
        float v0 = bf2f(vh[(size_t)s0 * HID + lane]);
        float g0 = 1.f / (1.f + __expf(-(kd + q0)));
        acc = fmaf(g0, v0, acc);
    }
    float xo = acc + skip[(size_t)node * HID + lane];
    outx[(size_t)node * HID + lane] = 0.5f * xo * (1.f + erff(xo * 0.70710678118f));
}

// ---------------------------------------------------------------------------
// Graph boundaries from sorted batch: start[g] = first node of graph g
// ---------------------------------------------------------------------------
__global__ __launch_bounds__(256) void bounds_kernel(
    const int* __restrict__ batch, int* __restrict__ start)
{
    int n = blockIdx.x * 256 + threadIdx.x;
    if (n >= N_NODES) return;
    int b  = batch[n];
    int bp = (n == 0) ? -1 : batch[n - 1];
    for (int g = bp + 1; g <= b; ++g) start[g] = n;
    if (n == N_NODES - 1) {
        for (int g = b + 1; g <= N_GRAPHS; ++g) start[g] = N_NODES;
    }
}

// ---------------------------------------------------------------------------
// Mean pool, segmented (batch sorted): one block per graph, no atomics.
// ---------------------------------------------------------------------------
__global__ __launch_bounds__(256) void pool2_kernel(
    const float* __restrict__ x, const int* __restrict__ start,
    float* __restrict__ pooled)
{
    int g    = blockIdx.x;
    int lane = threadIdx.x & 63;
    int wid  = threadIdx.x >> 6;
    int s0 = start[g];
    int s1 = start[g + 1];
    float acc = 0.f;
    for (int n = s0 + wid; n < s1; n += 4)
        acc += x[(size_t)n * HID + lane];
    __shared__ float red[4][64];
    red[wid][lane] = acc;
    __syncthreads();
    if (wid == 0) {
        float s = red[0][lane] + red[1][lane] + red[2][lane] + red[3][lane];
        float cnt = fmaxf((float)(s1 - s0), 1.f);
        pooled[(size_t)g * HID + lane] = s / cnt;
    }
}

// ---------------------------------------------------------------------------
// Head: h = relu(pooled@W1+b1); out = h@W2+b2. One block per graph.
// ---------------------------------------------------------------------------
__global__ __launch_bounds__(64) void head_kernel(
    const float* __restrict__ pooled,
    const float* __restrict__ w1, const float* __restrict__ b1,
    const float* __restrict__ w2, const float* __restrict__ b2,
    float* __restrict__ out)
{
    int g = blockIdx.x;
    int t = threadIdx.x;
    __shared__ float p[64];
    __shared__ float h[64];
    p[t] = pooled[(size_t)g * HID + t];
    __syncthreads();
    float acc = b1[t];
    #pragma unroll 8
    for (int k = 0; k < HID; ++k) acc = fmaf(p[k], w1[k * HID + t], acc);
    h[t] = fmaxf(acc, 0.f);
    __syncthreads();
    if (t < OUT_DIM) {
        float a2 = b2[t];
        #pragma unroll 8
        for (int k = 0; k < HID; ++k) a2 = fmaf(h[k], w2[k * OUT_DIM + t], a2);
        out[(size_t)g * OUT_DIM + t] = a2;
    }
}

// ---------------------------------------------------------------------------
extern "C" void kernel_launch(void* const* d_in, const int* in_sizes, int n_in,
                              void* d_out, int out_size, void* d_ws, size_t ws_size,
                              hipStream_t stream)
{
    const float* x     = (const float*)d_in[0];
    const int*   ei    = (const int*)d_in[1];
    const int*   batch = (const int*)d_in[2];
    const float* Wk = (const float*)d_in[4];
    const float* bk = (const float*)d_in[5];
    const float* Wq = (const float*)d_in[6];
    const float* bq = (const float*)d_in[7];
    const float* Wv = (const float*)d_in[8];
    const float* bv = (const float*)d_in[9];
    const float* Ws = (const float*)d_in[10];
    const float* bs = (const float*)d_in[11];
    const float* w1 = (const float*)d_in[12];
    const float* b1 = (const float*)d_in[13];
    const float* w2 = (const float*)d_in[14];
    const float* b2 = (const float*)d_in[15];
    float* out = (float*)d_out;

    char* wsb = (char*)d_ws;
    const size_t NF = (size_t)N_NODES * HID;
    float* bufA   = (float*)wsb;                    wsb += NF * 4;
    float* bufB   = (float*)wsb;                    wsb += NF * 4;
    float* bufK   = (float*)wsb;                    wsb += NF * 4;
    u16*   bufQh  = (u16*)wsb;                      wsb += NF * 2;
    u16*   bufVh  = (u16*)wsb;                      wsb += NF * 2;
    float* pooled = (float*)wsb;                    wsb += (size_t)N_GRAPHS * HID * 4;
    int*   baseI  = (int*)wsb;                      wsb += (N_NODES + 1) * 4;
    int*   csr_src= (int*)wsb;                      wsb += (size_t)N_EDGES * 4;
    int*   startI = (int*)wsb;                      wsb += (N_GRAPHS + 1) * 4;
    // transient CSR-build scratch overlaps bufB (first written in layer 1)
    int* deg      = (int*)bufB;
    int* cursor   = deg + N_NODES;
    int* blocksum = cursor + N_NODES;
    int* blockoff = blocksum + 128;

    const int gemm_gx = (N_NODES + 63) / 64;          // 782
    const int eg      = (N_EDGES + 255) / 256;        // 3125
    const int agg_g   = (N_NODES + 3) / 4;            // 12500
    const int nd_g    = (N_NODES + 255) / 256;        // 196

    // ---- build CSR (dst -> list of src) + graph bounds, once ----
    hipMemsetAsync(deg, 0, (size_t)2 * N_NODES * sizeof(int), stream);
    hist_kernel<<<eg, 256, 0, stream>>>(ei, deg);
    scan1_kernel<<<N_CHUNKS, SCAN_CHUNK, 0, stream>>>(deg, baseI, blocksum);
    scan2_kernel<<<1, 128, 0, stream>>>(blocksum, blockoff);
    scan3_kernel<<<N_CHUNKS, SCAN_CHUNK, 0, stream>>>(baseI, blockoff);
    scatter_kernel<<<eg, 256, 0, stream>>>(ei, baseI, cursor, csr_src);
    bounds_kernel<<<nd_g, 256, 0, stream>>>(batch, startI);

    // ---- layers ----
    const float* xsrc = x;
    for (int l = 0; l < N_LAYERS; ++l) {
        float* sb = (l & 1) ? bufB : bufA;
        gemm4f_kernel<<<gemm_gx, 256, 0, stream>>>(
            xsrc,
            Wk + (size_t)l * HID * HID, bk + (size_t)l * HID,
            Wq + (size_t)l * HID * HID, bq + (size_t)l * HID,
            Wv + (size_t)l * HID * HID, bv + (size_t)l * HID,
            Ws + (size_t)l * HID * HID, bs + (size_t)l * HID,
            bufK, bufQh, bufVh, sb);
        agg_gelu_kernel<<<agg_g, 256, 0, stream>>>(
            baseI, csr_src, bufK, bufQh, bufVh, sb, sb);
        xsrc = sb;
    }

    // ---- pool + head ----
    pool2_kernel<<<N_GRAPHS, 256, 0, stream>>>(xsrc, startI, pooled);
    head_kernel<<<N_GRAPHS, 64, 0, stream>>>(pooled, w1, b1, w2, b2, out);
}

// Round 4
// 461.559 us; speedup vs baseline: 6.9217x; 1.2326x over previous
//
#include <hip/hip_runtime.h>
#include <math.h>

#define N_NODES  50000
#define N_EDGES  800000
#define HID      64
#define OUT_DIM  12
#define N_LAYERS 4
#define N_GRAPHS 512

#define SCAN_CHUNK 512
#define N_CHUNKS   ((N_NODES + SCAN_CHUNK - 1) / SCAN_CHUNK)   // 98

typedef unsigned short u16;
typedef unsigned int   u32;

__device__ __forceinline__ u16 f2bf(float f) {
    u32 u = __float_as_uint(f);
    u32 r = (u + 0x7FFFu + ((u >> 16) & 1u)) >> 16;   // RNE
    return (u16)r;
}
__device__ __forceinline__ float bf2f(u32 h) {
    return __uint_as_float(h << 16);
}

// ---------------------------------------------------------------------------
// Fused 2-matrix GEMM: blockIdx.y=0 -> (Wk->f32 ok, Wq->bf16 oq)
//                      blockIdx.y=1 -> (Ws->f32 os, Wv->bf16 ov)
// 64-node tile, 256 threads, each thread 4 nodes x 4 cols x 2 mats = 32 acc.
// Weights from global (L1/L2-resident).
// ---------------------------------------------------------------------------
__global__ __launch_bounds__(256) void gemm2m_kernel(
    const float* __restrict__ x,
    const float* __restrict__ Wk, const float* __restrict__ bk,
    const float* __restrict__ Wq, const float* __restrict__ bq,
    const float* __restrict__ Wv, const float* __restrict__ bv,
    const float* __restrict__ Ws, const float* __restrict__ bs,
    float* __restrict__ ok, u16* __restrict__ oq,
    u16* __restrict__ ov, float* __restrict__ os)
{
    __shared__ float xs[64][65];   // +1 pad
    const int t = threadIdx.x;
    const int gbase = blockIdx.x * 64;

    const float *Wa, *ba, *Wb, *bb;
    float* oa; u16* ob;
    if (blockIdx.y == 0) { Wa = Wk; ba = bk; oa = ok; Wb = Wq; bb = bq; ob = oq; }
    else                 { Wa = Ws; ba = bs; oa = os; Wb = Wv; bb = bv; ob = ov; }

    #pragma unroll
    for (int i = 0; i < 4; ++i) {
        int idx = t + i * 256;        // float4 index 0..1023
        int r   = idx >> 4;
        int c4  = idx & 15;
        int gn  = gbase + r;
        float4 val = make_float4(0.f, 0.f, 0.f, 0.f);
        if (gn < N_NODES) val = *(const float4*)(x + (size_t)gn * HID + c4 * 4);
        xs[r][c4 * 4 + 0] = val.x; xs[r][c4 * 4 + 1] = val.y;
        xs[r][c4 * 4 + 2] = val.z; xs[r][c4 * 4 + 3] = val.w;
    }
    __syncthreads();

    const int cg = (t & 15) * 4;   // col group
    const int ng = (t >> 4) * 4;   // node group within tile

    float acc[2][4][4];            // [mat][node][col]
    {
        float4 ba4 = *(const float4*)(ba + cg);
        float4 bb4 = *(const float4*)(bb + cg);
        #pragma unroll
        for (int i = 0; i < 4; ++i) {
            acc[0][i][0] = ba4.x; acc[0][i][1] = ba4.y; acc[0][i][2] = ba4.z; acc[0][i][3] = ba4.w;
            acc[1][i][0] = bb4.x; acc[1][i][1] = bb4.y; acc[1][i][2] = bb4.z; acc[1][i][3] = bb4.w;
        }
    }

    #pragma unroll 8
    for (int k = 0; k < 64; ++k) {
        float xr[4];
        #pragma unroll
        for (int i = 0; i < 4; ++i) xr[i] = xs[ng + i][k];
        float4 wa = *(const float4*)(Wa + k * HID + cg);
        float4 wb = *(const float4*)(Wb + k * HID + cg);
        #pragma unroll
        for (int i = 0; i < 4; ++i) {
            acc[0][i][0] = fmaf(xr[i], wa.x, acc[0][i][0]);
            acc[0][i][1] = fmaf(xr[i], wa.y, acc[0][i][1]);
            acc[0][i][2] = fmaf(xr[i], wa.z, acc[0][i][2]);
            acc[0][i][3] = fmaf(xr[i], wa.w, acc[0][i][3]);
            acc[1][i][0] = fmaf(xr[i], wb.x, acc[1][i][0]);
            acc[1][i][1] = fmaf(xr[i], wb.y, acc[1][i][1]);
            acc[1][i][2] = fmaf(xr[i], wb.z, acc[1][i][2]);
            acc[1][i][3] = fmaf(xr[i], wb.w, acc[1][i][3]);
        }
    }

    #pragma unroll
    for (int i = 0; i < 4; ++i) {
        int gn = gbase + ng + i;
        if (gn < N_NODES) {
            size_t off = (size_t)gn * HID + cg;
            *(float4*)(oa + off) = make_float4(acc[0][i][0], acc[0][i][1], acc[0][i][2], acc[0][i][3]);
            u32 b01 = (u32)f2bf(acc[1][i][0]) | ((u32)f2bf(acc[1][i][1]) << 16);
            u32 b23 = (u32)f2bf(acc[1][i][2]) | ((u32)f2bf(acc[1][i][3]) << 16);
            *(uint2*)(ob + off) = make_uint2(b01, b23);
        }
    }
}

// ---------------------------------------------------------------------------
// CSR build: histogram of dst, exclusive scan, scatter of src ids
// ---------------------------------------------------------------------------
__global__ __launch_bounds__(256) void hist_kernel(
    const int* __restrict__ ei, int* __restrict__ deg)
{
    int e = blockIdx.x * 256 + threadIdx.x;
    if (e < N_EDGES) atomicAdd(&deg[ei[N_EDGES + e]], 1);
}

__global__ __launch_bounds__(SCAN_CHUNK) void scan1_kernel(
    const int* __restrict__ deg, int* __restrict__ base, int* __restrict__ blocksum)
{
    __shared__ int s[SCAN_CHUNK];
    int t = threadIdx.x;
    int i = blockIdx.x * SCAN_CHUNK + t;
    int v = (i < N_NODES) ? deg[i] : 0;
    s[t] = v;
    __syncthreads();
    for (int off = 1; off < SCAN_CHUNK; off <<= 1) {
        int u = (t >= off) ? s[t - off] : 0;
        __syncthreads();
        s[t] += u;
        __syncthreads();
    }
    if (i < N_NODES) base[i] = s[t] - v;              // exclusive
    if (t == SCAN_CHUNK - 1) blocksum[blockIdx.x] = s[t];
}

__global__ __launch_bounds__(128) void scan2_kernel(
    const int* __restrict__ blocksum, int* __restrict__ blockoff)
{
    __shared__ int s[128];
    int t = threadIdx.x;
    int v = (t < N_CHUNKS) ? blocksum[t] : 0;
    s[t] = v;
    __syncthreads();
    for (int off = 1; off < 128; off <<= 1) {
        int u = (t >= off) ? s[t - off] : 0;
        __syncthreads();
        s[t] += u;
        __syncthreads();
    }
    if (t < N_CHUNKS) blockoff[t] = s[t] - v;         // exclusive
}

__global__ __launch_bounds__(SCAN_CHUNK) void scan3_kernel(
    int* __restrict__ base, const int* __restrict__ blockoff)
{
    int i = blockIdx.x * SCAN_CHUNK + threadIdx.x;
    if (i < N_NODES) base[i] += blockoff[blockIdx.x];
    if (i == 0) base[N_NODES] = N_EDGES;
}

__global__ __launch_bounds__(256) void scatter_kernel(
    const int* __restrict__ ei, const int* __restrict__ base,
    int* __restrict__ cursor, int* __restrict__ csr_src)
{
    int e = blockIdx.x * 256 + threadIdx.x;
    if (e >= N_EDGES) return;
    int s = ei[e];
    int d = ei[N_EDGES + e];
    int pos = base[d] + atomicAdd(&cursor[d], 1);
    csr_src[pos] = s;
}

// ---------------------------------------------------------------------------
// Gather aggregation + skip + GELU. One wave per node.
// Lane = (half, chanpair): lanes 0-31 process even edges, 32-63 odd edges;
// each lane covers channels {2c, 2c+1} via packed-bf16 u32 loads.
// ---------------------------------------------------------------------------
__global__ __launch_bounds__(256) void agg_gelu_kernel(
    const int* __restrict__ base, const int* __restrict__ csr_src,
    const float* __restrict__ kf, const u32* __restrict__ qw,
    const u32* __restrict__ vw, const float* __restrict__ skip,
    float* __restrict__ outx)
{
    int node = blockIdx.x * 4 + (threadIdx.x >> 6);
    if (node >= N_NODES) return;
    int lane = threadIdx.x & 63;
    int half = lane >> 5;
    int c    = lane & 31;             // channel pair: 2c, 2c+1

    float2 kd = *(const float2*)(kf + (size_t)node * HID + 2 * c);
    float acc0 = 0.f, acc1 = 0.f;
    int p0 = base[node];
    int p1 = base[node + 1];

    #pragma unroll 2
    for (int p = p0 + half; p < p1; p += 2) {
        int s = csr_src[p];
        u32 qp = qw[(size_t)s * 32 + c];
        u32 vp = vw[(size_t)s * 32 + c];
        float q0 = bf2f(qp & 0xffffu), q1 = bf2f(qp >> 16);
        float v0 = bf2f(vp & 0xffffu), v1 = bf2f(vp >> 16);
        float g0 = 1.f / (1.f + __expf(-(kd.x + q0)));
        float g1 = 1.f / (1.f + __expf(-(kd.y + q1)));
        acc0 = fmaf(g0, v0, acc0);
        acc1 = fmaf(g1, v1, acc1);
    }

    // combine the two half-wave partial sums (lane l <-> lane l^32)
    acc0 += __shfl_xor(acc0, 32);
    acc1 += __shfl_xor(acc1, 32);

    if (half == 0) {
        float2 sk = *(const float2*)(skip + (size_t)node * HID + 2 * c);
        float xo0 = acc0 + sk.x;
        float xo1 = acc1 + sk.y;
        float g0 = 0.5f * xo0 * (1.f + erff(xo0 * 0.70710678118f));
        float g1 = 0.5f * xo1 * (1.f + erff(xo1 * 0.70710678118f));
        *(float2*)(outx + (size_t)node * HID + 2 * c) = make_float2(g0, g1);
    }
}

// ---------------------------------------------------------------------------
// Graph boundaries from sorted batch: start[g] = first node of graph g
// ---------------------------------------------------------------------------
__global__ __launch_bounds__(256) void bounds_kernel(
    const int* __restrict__ batch, int* __restrict__ start)
{
    int n = blockIdx.x * 256 + threadIdx.x;
    if (n >= N_NODES) return;
    int b  = batch[n];
    int bp = (n == 0) ? -1 : batch[n - 1];
    for (int g = bp + 1; g <= b; ++g) start[g] = n;
    if (n == N_NODES - 1) {
        for (int g = b + 1; g <= N_GRAPHS; ++g) start[g] = N_NODES;
    }
}

// ---------------------------------------------------------------------------
// Mean pool, segmented (batch sorted): one block per graph, no atomics.
// ---------------------------------------------------------------------------
__global__ __launch_bounds__(256) void pool2_kernel(
    const float* __restrict__ x, const int* __restrict__ start,
    float* __restrict__ pooled)
{
    int g    = blockIdx.x;
    int lane = threadIdx.x & 63;
    int wid  = threadIdx.x >> 6;
    int s0 = start[g];
    int s1 = start[g + 1];
    float acc = 0.f;
    for (int n = s0 + wid; n < s1; n += 4)
        acc += x[(size_t)n * HID + lane];
    __shared__ float red[4][64];
    red[wid][lane] = acc;
    __syncthreads();
    if (wid == 0) {
        float s = red[0][lane] + red[1][lane] + red[2][lane] + red[3][lane];
        float cnt = fmaxf((float)(s1 - s0), 1.f);
        pooled[(size_t)g * HID + lane] = s / cnt;
    }
}

// ---------------------------------------------------------------------------
// Head: h = relu(pooled@W1+b1); out = h@W2+b2. One block per graph.
// ---------------------------------------------------------------------------
__global__ __launch_bounds__(64) void head_kernel(
    const float* __restrict__ pooled,
    const float* __restrict__ w1, const float* __restrict__ b1,
    const float* __restrict__ w2, const float* __restrict__ b2,
    float* __restrict__ out)
{
    int g = blockIdx.x;
    int t = threadIdx.x;
    __shared__ float p[64];
    __shared__ float h[64];
    p[t] = pooled[(size_t)g * HID + t];
    __syncthreads();
    float acc = b1[t];
    #pragma unroll 8
    for (int k = 0; k < HID; ++k) acc = fmaf(p[k], w1[k * HID + t], acc);
    h[t] = fmaxf(acc, 0.f);
    __syncthreads();
    if (t < OUT_DIM) {
        float a2 = b2[t];
        #pragma unroll 8
        for (int k = 0; k < HID; ++k) a2 = fmaf(h[k], w2[k * OUT_DIM + t], a2);
        out[(size_t)g * OUT_DIM + t] = a2;
    }
}

// ---------------------------------------------------------------------------
extern "C" void kernel_launch(void* const* d_in, const int* in_sizes, int n_in,
                              void* d_out, int out_size, void* d_ws, size_t ws_size,
                              hipStream_t stream)
{
    const float* x     = (const float*)d_in[0];
    const int*   ei    = (const int*)d_in[1];
    const int*   batch = (const int*)d_in[2];
    const float* Wk = (const float*)d_in[4];
    const float* bk = (const float*)d_in[5];
    const float* Wq = (const float*)d_in[6];
    const float* bq = (const float*)d_in[7];
    const float* Wv = (const float*)d_in[8];
    const float* bv = (const float*)d_in[9];
    const float* Ws = (const float*)d_in[10];
    const float* bs = (const float*)d_in[11];
    const float* w1 = (const float*)d_in[12];
    const float* b1 = (const float*)d_in[13];
    const float* w2 = (const float*)d_in[14];
    const float* b2 = (const float*)d_in[15];
    float* out = (float*)d_out;

    char* wsb = (char*)d_ws;
    const size_t NF = (size_t)N_NODES * HID;
    float* bufA   = (float*)wsb;                    wsb += NF * 4;
    float* bufB   = (float*)wsb;                    wsb += NF * 4;
    float* bufK   = (float*)wsb;                    wsb += NF * 4;
    u16*   bufQh  = (u16*)wsb;                      wsb += NF * 2;
    u16*   bufVh  = (u16*)wsb;                      wsb += NF * 2;
    float* pooled = (float*)wsb;                    wsb += (size_t)N_GRAPHS * HID * 4;
    int*   baseI  = (int*)wsb;                      wsb += (N_NODES + 1) * 4;
    int*   csr_src= (int*)wsb;                      wsb += (size_t)N_EDGES * 4;
    int*   startI = (int*)wsb;                      wsb += (N_GRAPHS + 1) * 4;
    // transient CSR-build scratch overlaps bufB (first written in layer 1)
    int* deg      = (int*)bufB;
    int* cursor   = deg + N_NODES;
    int* blocksum = cursor + N_NODES;
    int* blockoff = blocksum + 128;

    const int gemm_gx = (N_NODES + 63) / 64;          // 782
    const int eg      = (N_EDGES + 255) / 256;        // 3125
    const int agg_g   = (N_NODES + 3) / 4;            // 12500
    const int nd_g    = (N_NODES + 255) / 256;        // 196

    // ---- build CSR (dst -> list of src) + graph bounds, once ----
    hipMemsetAsync(deg, 0, (size_t)2 * N_NODES * sizeof(int), stream);
    hist_kernel<<<eg, 256, 0, stream>>>(ei, deg);
    scan1_kernel<<<N_CHUNKS, SCAN_CHUNK, 0, stream>>>(deg, baseI, blocksum);
    scan2_kernel<<<1, 128, 0, stream>>>(blocksum, blockoff);
    scan3_kernel<<<N_CHUNKS, SCAN_CHUNK, 0, stream>>>(baseI, blockoff);
    scatter_kernel<<<eg, 256, 0, stream>>>(ei, baseI, cursor, csr_src);
    bounds_kernel<<<nd_g, 256, 0, stream>>>(batch, startI);

    // ---- layers ----
    const float* xsrc = x;
    for (int l = 0; l < N_LAYERS; ++l) {
        float* sb = (l & 1) ? bufB : bufA;
        gemm2m_kernel<<<dim3(gemm_gx, 2), 256, 0, stream>>>(
            xsrc,
            Wk + (size_t)l * HID * HID, bk + (size_t)l * HID,
            Wq + (size_t)l * HID * HID, bq + (size_t)l * HID,
            Wv + (size_t)l * HID * HID, bv + (size_t)l * HID,
            Ws + (size_t)l * HID * HID, bs + (size_t)l * HID,
            bufK, bufQh, bufVh, sb);
        agg_gelu_kernel<<<agg_g, 256, 0, stream>>>(
            baseI, csr_src, bufK, (const u32*)bufQh, (const u32*)bufVh, sb, sb);
        xsrc = sb;
    }

    // ---- pool + head ----
    pool2_kernel<<<N_GRAPHS, 256, 0, stream>>>(xsrc, startI, pooled);
    head_kernel<<<N_GRAPHS, 64, 0, stream>>>(pooled, w1, b1, w2, b2, out);
}

// Round 5
// 413.622 us; speedup vs baseline: 7.7239x; 1.1159x over previous
//
#include <hip/hip_runtime.h>
#include <math.h>

#define N_NODES  50000
#define N_EDGES  800000
#define HID      64
#define OUT_DIM  12
#define N_LAYERS 4
#define N_GRAPHS 512

#define SCAN_CHUNK 512
#define N_CHUNKS   ((N_NODES + SCAN_CHUNK - 1) / SCAN_CHUNK)   // 98

typedef unsigned short u16;
typedef unsigned int   u32;

__device__ __forceinline__ u16 f2bf(float f) {
    u32 u = __float_as_uint(f);
    u32 r = (u + 0x7FFFu + ((u >> 16) & 1u)) >> 16;   // RNE
    return (u16)r;
}
__device__ __forceinline__ float bf2f(u32 h) {
    return __uint_as_float(h << 16);
}

// ---------------------------------------------------------------------------
// Fused 2-matrix GEMM, weights staged in LDS (no global loads in k-loop).
//   blockIdx.y=0 -> (Wq, Wv) -> interleaved bf16 qv buffer
//   blockIdx.y=1 -> (Wk, Ws) -> f32 ok, os
// 64-node tile, 256 threads, each thread 4 nodes x 4 cols x 2 mats.
// qv layout (u32 units): qv[node*64 + 2*p + 0] = q channel-pair p,
//                        qv[node*64 + 2*p + 1] = v channel-pair p.
// ---------------------------------------------------------------------------
__global__ __launch_bounds__(256) void gemm2m_kernel(
    const float* __restrict__ x,
    const float* __restrict__ Wq, const float* __restrict__ bq,
    const float* __restrict__ Wv, const float* __restrict__ bv,
    const float* __restrict__ Wk, const float* __restrict__ bk,
    const float* __restrict__ Ws, const float* __restrict__ bs,
    u32* __restrict__ qv, float* __restrict__ ok, float* __restrict__ os)
{
    __shared__ float xs[64][65];        // +1 pad
    __shared__ float wsm[2][64][64];    // both weight matrices, f32
    const int t = threadIdx.x;
    const int gbase = blockIdx.x * 64;

    const float *Wa, *ba, *Wb, *bb;
    if (blockIdx.y == 0) { Wa = Wq; ba = bq; Wb = Wv; bb = bv; }
    else                 { Wa = Wk; ba = bk; Wb = Ws; bb = bs; }

    // stage x tile (1024 float4) + both W (2 x 1024 float4)
    #pragma unroll
    for (int i = 0; i < 4; ++i) {
        int idx = t + i * 256;        // float4 index 0..1023
        int r   = idx >> 4;
        int c4  = idx & 15;
        int gn  = gbase + r;
        float4 val = make_float4(0.f, 0.f, 0.f, 0.f);
        if (gn < N_NODES) val = *(const float4*)(x + (size_t)gn * HID + c4 * 4);
        xs[r][c4 * 4 + 0] = val.x; xs[r][c4 * 4 + 1] = val.y;
        xs[r][c4 * 4 + 2] = val.z; xs[r][c4 * 4 + 3] = val.w;
        *(float4*)&wsm[0][r][c4 * 4] = *(const float4*)(Wa + r * HID + c4 * 4);
        *(float4*)&wsm[1][r][c4 * 4] = *(const float4*)(Wb + r * HID + c4 * 4);
    }
    __syncthreads();

    const int cg = (t & 15) * 4;   // col group
    const int ng = (t >> 4) * 4;   // node group within tile

    float acc[2][4][4];            // [mat][node][col]
    {
        float4 ba4 = *(const float4*)(ba + cg);
        float4 bb4 = *(const float4*)(bb + cg);
        #pragma unroll
        for (int i = 0; i < 4; ++i) {
            acc[0][i][0] = ba4.x; acc[0][i][1] = ba4.y; acc[0][i][2] = ba4.z; acc[0][i][3] = ba4.w;
            acc[1][i][0] = bb4.x; acc[1][i][1] = bb4.y; acc[1][i][2] = bb4.z; acc[1][i][3] = bb4.w;
        }
    }

    #pragma unroll 8
    for (int k = 0; k < 64; ++k) {
        float xr[4];
        #pragma unroll
        for (int i = 0; i < 4; ++i) xr[i] = xs[ng + i][k];
        float4 wa = *(float4*)&wsm[0][k][cg];
        float4 wb = *(float4*)&wsm[1][k][cg];
        #pragma unroll
        for (int i = 0; i < 4; ++i) {
            acc[0][i][0] = fmaf(xr[i], wa.x, acc[0][i][0]);
            acc[0][i][1] = fmaf(xr[i], wa.y, acc[0][i][1]);
            acc[0][i][2] = fmaf(xr[i], wa.z, acc[0][i][2]);
            acc[0][i][3] = fmaf(xr[i], wa.w, acc[0][i][3]);
            acc[1][i][0] = fmaf(xr[i], wb.x, acc[1][i][0]);
            acc[1][i][1] = fmaf(xr[i], wb.y, acc[1][i][1]);
            acc[1][i][2] = fmaf(xr[i], wb.z, acc[1][i][2]);
            acc[1][i][3] = fmaf(xr[i], wb.w, acc[1][i][3]);
        }
    }

    if (blockIdx.y == 0) {
        // interleaved bf16 (q,v): uint4 = (q01, v01, q23, v23) at u32-offset node*64+cg
        #pragma unroll
        for (int i = 0; i < 4; ++i) {
            int gn = gbase + ng + i;
            if (gn < N_NODES) {
                u32 q01 = (u32)f2bf(acc[0][i][0]) | ((u32)f2bf(acc[0][i][1]) << 16);
                u32 q23 = (u32)f2bf(acc[0][i][2]) | ((u32)f2bf(acc[0][i][3]) << 16);
                u32 v01 = (u32)f2bf(acc[1][i][0]) | ((u32)f2bf(acc[1][i][1]) << 16);
                u32 v23 = (u32)f2bf(acc[1][i][2]) | ((u32)f2bf(acc[1][i][3]) << 16);
                *(uint4*)(qv + (size_t)gn * 64 + cg) = make_uint4(q01, v01, q23, v23);
            }
        }
    } else {
        #pragma unroll
        for (int i = 0; i < 4; ++i) {
            int gn = gbase + ng + i;
            if (gn < N_NODES) {
                size_t off = (size_t)gn * HID + cg;
                *(float4*)(ok + off) = make_float4(acc[0][i][0], acc[0][i][1], acc[0][i][2], acc[0][i][3]);
                *(float4*)(os + off) = make_float4(acc[1][i][0], acc[1][i][1], acc[1][i][2], acc[1][i][3]);
            }
        }
    }
}

// ---------------------------------------------------------------------------
// CSR build: histogram of dst, exclusive scan, scatter of src ids
// ---------------------------------------------------------------------------
__global__ __launch_bounds__(256) void hist_kernel(
    const int* __restrict__ ei, int* __restrict__ deg)
{
    int e = blockIdx.x * 256 + threadIdx.x;
    if (e < N_EDGES) atomicAdd(&deg[ei[N_EDGES + e]], 1);
}

__global__ __launch_bounds__(SCAN_CHUNK) void scan1_kernel(
    const int* __restrict__ deg, int* __restrict__ base, int* __restrict__ blocksum)
{
    __shared__ int s[SCAN_CHUNK];
    int t = threadIdx.x;
    int i = blockIdx.x * SCAN_CHUNK + t;
    int v = (i < N_NODES) ? deg[i] : 0;
    s[t] = v;
    __syncthreads();
    for (int off = 1; off < SCAN_CHUNK; off <<= 1) {
        int u = (t >= off) ? s[t - off] : 0;
        __syncthreads();
        s[t] += u;
        __syncthreads();
    }
    if (i < N_NODES) base[i] = s[t] - v;              // exclusive
    if (t == SCAN_CHUNK - 1) blocksum[blockIdx.x] = s[t];
}

__global__ __launch_bounds__(128) void scan2_kernel(
    const int* __restrict__ blocksum, int* __restrict__ blockoff)
{
    __shared__ int s[128];
    int t = threadIdx.x;
    int v = (t < N_CHUNKS) ? blocksum[t] : 0;
    s[t] = v;
    __syncthreads();
    for (int off = 1; off < 128; off <<= 1) {
        int u = (t >= off) ? s[t - off] : 0;
        __syncthreads();
        s[t] += u;
        __syncthreads();
    }
    if (t < N_CHUNKS) blockoff[t] = s[t] - v;         // exclusive
}

__global__ __launch_bounds__(SCAN_CHUNK) void scan3_kernel(
    int* __restrict__ base, const int* __restrict__ blockoff)
{
    int i = blockIdx.x * SCAN_CHUNK + threadIdx.x;
    if (i < N_NODES) base[i] += blockoff[blockIdx.x];
    if (i == 0) base[N_NODES] = N_EDGES;
}

__global__ __launch_bounds__(256) void scatter_kernel(
    const int* __restrict__ ei, const int* __restrict__ base,
    int* __restrict__ cursor, int* __restrict__ csr_src)
{
    int e = blockIdx.x * 256 + threadIdx.x;
    if (e >= N_EDGES) return;
    int s = ei[e];
    int d = ei[N_EDGES + e];
    int pos = base[d] + atomicAdd(&cursor[d], 1);
    csr_src[pos] = s;
}

// ---------------------------------------------------------------------------
// Gather aggregation + skip + GELU. One wave per node.
// Lanes 0-31 process even edges, 32-63 odd edges; lane covers channels
// {2c,2c+1} via one uint2 load from the interleaved bf16 qv buffer.
// ---------------------------------------------------------------------------
__global__ __launch_bounds__(256) void agg_gelu_kernel(
    const int* __restrict__ base, const int* __restrict__ csr_src,
    const float* __restrict__ kf, const u32* __restrict__ qv,
    const float* __restrict__ skip, float* __restrict__ outx)
{
    int node = blockIdx.x * 4 + (threadIdx.x >> 6);
    if (node >= N_NODES) return;
    int lane = threadIdx.x & 63;
    int half = lane >> 5;
    int c    = lane & 31;             // channel pair: 2c, 2c+1

    float2 kd = *(const float2*)(kf + (size_t)node * HID + 2 * c);
    float acc0 = 0.f, acc1 = 0.f;
    int p0 = base[node];
    int p1 = base[node + 1];

    #pragma unroll 2
    for (int p = p0 + half; p < p1; p += 2) {
        int s = csr_src[p];
        uint2 qp = *(const uint2*)(qv + (size_t)s * 64 + 2 * c);
        float q0 = bf2f(qp.x & 0xffffu), q1 = bf2f(qp.x >> 16);
        float v0 = bf2f(qp.y & 0xffffu), v1 = bf2f(qp.y >> 16);
        float g0 = 1.f / (1.f + __expf(-(kd.x + q0)));
        float g1 = 1.f / (1.f + __expf(-(kd.y + q1)));
        acc0 = fmaf(g0, v0, acc0);
        acc1 = fmaf(g1, v1, acc1);
    }

    // combine the two half-wave partial sums (lane l <-> lane l^32)
    acc0 += __shfl_xor(acc0, 32);
    acc1 += __shfl_xor(acc1, 32);

    if (half == 0) {
        float2 sk = *(const float2*)(skip + (size_t)node * HID + 2 * c);
        float xo0 = acc0 + sk.x;
        float xo1 = acc1 + sk.y;
        float g0 = 0.5f * xo0 * (1.f + erff(xo0 * 0.70710678118f));
        float g1 = 0.5f * xo1 * (1.f + erff(xo1 * 0.70710678118f));
        *(float2*)(outx + (size_t)node * HID + 2 * c) = make_float2(g0, g1);
    }
}

// ---------------------------------------------------------------------------
// Graph boundaries from sorted batch: start[g] = first node of graph g
// ---------------------------------------------------------------------------
__global__ __launch_bounds__(256) void bounds_kernel(
    const int* __restrict__ batch, int* __restrict__ start)
{
    int n = blockIdx.x * 256 + threadIdx.x;
    if (n >= N_NODES) return;
    int b  = batch[n];
    int bp = (n == 0) ? -1 : batch[n - 1];
    for (int g = bp + 1; g <= b; ++g) start[g] = n;
    if (n == N_NODES - 1) {
        for (int g = b + 1; g <= N_GRAPHS; ++g) start[g] = N_NODES;
    }
}

// ---------------------------------------------------------------------------
// Mean pool, segmented (batch sorted): one block per graph, no atomics.
// ---------------------------------------------------------------------------
__global__ __launch_bounds__(256) void pool2_kernel(
    const float* __restrict__ x, const int* __restrict__ start,
    float* __restrict__ pooled)
{
    int g    = blockIdx.x;
    int lane = threadIdx.x & 63;
    int wid  = threadIdx.x >> 6;
    int s0 = start[g];
    int s1 = start[g + 1];
    float acc = 0.f;
    for (int n = s0 + wid; n < s1; n += 4)
        acc += x[(size_t)n * HID + lane];
    __shared__ float red[4][64];
    red[wid][lane] = acc;
    __syncthreads();
    if (wid == 0) {
        float s = red[0][lane] + red[1][lane] + red[2][lane] + red[3][lane];
        float cnt = fmaxf((float)(s1 - s0), 1.f);
        pooled[(size_t)g * HID + lane] = s / cnt;
    }
}

// ---------------------------------------------------------------------------
// Head: h = relu(pooled@W1+b1); out = h@W2+b2. One block per graph.
// ---------------------------------------------------------------------------
__global__ __launch_bounds__(64) void head_kernel(
    const float* __restrict__ pooled,
    const float* __restrict__ w1, const float* __restrict__ b1,
    const float* __restrict__ w2, const float* __restrict__ b2,
    float* __restrict__ out)
{
    int g = blockIdx.x;
    int t = threadIdx.x;
    __shared__ float p[64];
    __shared__ float h[64];
    p[t] = pooled[(size_t)g * HID + t];
    __syncthreads();
    float acc = b1[t];
    #pragma unroll 8
    for (int k = 0; k < HID; ++k) acc = fmaf(p[k], w1[k * HID + t], acc);
    h[t] = fmaxf(acc, 0.f);
    __syncthreads();
    if (t < OUT_DIM) {
        float a2 = b2[t];
        #pragma unroll 8
        for (int k = 0; k < HID; ++k) a2 = fmaf(h[k], w2[k * OUT_DIM + t], a2);
        out[(size_t)g * OUT_DIM + t] = a2;
    }
}

// ---------------------------------------------------------------------------
extern "C" void kernel_launch(void* const* d_in, const int* in_sizes, int n_in,
                              void* d_out, int out_size, void* d_ws, size_t ws_size,
                              hipStream_t stream)
{
    const float* x     = (const float*)d_in[0];
    const int*   ei    = (const int*)d_in[1];
    const int*   batch = (const int*)d_in[2];
    const float* Wk = (const float*)d_in[4];
    const float* bk = (const float*)d_in[5];
    const float* Wq = (const float*)d_in[6];
    const float* bq = (const float*)d_in[7];
    const float* Wv = (const float*)d_in[8];
    const float* bv = (const float*)d_in[9];
    const float* Ws = (const float*)d_in[10];
    const float* bs = (const float*)d_in[11];
    const float* w1 = (const float*)d_in[12];
    const float* b1 = (const float*)d_in[13];
    const float* w2 = (const float*)d_in[14];
    const float* b2 = (const float*)d_in[15];
    float* out = (float*)d_out;

    char* wsb = (char*)d_ws;
    const size_t NF = (size_t)N_NODES * HID;
    float* bufA   = (float*)wsb;                    wsb += NF * 4;
    float* bufB   = (float*)wsb;                    wsb += NF * 4;
    float* bufK   = (float*)wsb;                    wsb += NF * 4;
    u32*   bufQV  = (u32*)wsb;                      wsb += NF * 4;   // interleaved bf16 q,v
    float* pooled = (float*)wsb;                    wsb += (size_t)N_GRAPHS * HID * 4;
    int*   baseI  = (int*)wsb;                      wsb += (N_NODES + 1) * 4;
    int*   csr_src= (int*)wsb;                      wsb += (size_t)N_EDGES * 4;
    int*   startI = (int*)wsb;                      wsb += (N_GRAPHS + 1) * 4;
    // transient CSR-build scratch overlaps bufB (first written in layer 1)
    int* deg      = (int*)bufB;
    int* cursor   = deg + N_NODES;
    int* blocksum = cursor + N_NODES;
    int* blockoff = blocksum + 128;

    const int gemm_gx = (N_NODES + 63) / 64;          // 782
    const int eg      = (N_EDGES + 255) / 256;        // 3125
    const int agg_g   = (N_NODES + 3) / 4;            // 12500
    const int nd_g    = (N_NODES + 255) / 256;        // 196

    // ---- build CSR (dst -> list of src) + graph bounds, once ----
    hipMemsetAsync(deg, 0, (size_t)2 * N_NODES * sizeof(int), stream);
    hist_kernel<<<eg, 256, 0, stream>>>(ei, deg);
    scan1_kernel<<<N_CHUNKS, SCAN_CHUNK, 0, stream>>>(deg, baseI, blocksum);
    scan2_kernel<<<1, 128, 0, stream>>>(blocksum, blockoff);
    scan3_kernel<<<N_CHUNKS, SCAN_CHUNK, 0, stream>>>(baseI, blockoff);
    scatter_kernel<<<eg, 256, 0, stream>>>(ei, baseI, cursor, csr_src);
    bounds_kernel<<<nd_g, 256, 0, stream>>>(batch, startI);

    // ---- layers ----
    const float* xsrc = x;
    for (int l = 0; l < N_LAYERS; ++l) {
        float* sb = (l & 1) ? bufB : bufA;
        gemm2m_kernel<<<dim3(gemm_gx, 2), 256, 0, stream>>>(
            xsrc,
            Wq + (size_t)l * HID * HID, bq + (size_t)l * HID,
            Wv + (size_t)l * HID * HID, bv + (size_t)l * HID,
            Wk + (size_t)l * HID * HID, bk + (size_t)l * HID,
            Ws + (size_t)l * HID * HID, bs + (size_t)l * HID,
            bufQV, bufK, sb);
        agg_gelu_kernel<<<agg_g, 256, 0, stream>>>(
            baseI, csr_src, bufK, bufQV, sb, sb);
        xsrc = sb;
    }

    // ---- pool + head ----
    pool2_kernel<<<N_GRAPHS, 256, 0, stream>>>(xsrc, startI, pooled);
    head_kernel<<<N_GRAPHS, 64, 0, stream>>>(pooled, w1, b1, w2, b2, out);
}